// Round 5
// baseline (423.907 us; speedup 1.0000x reference)
//
#include <hip/hip_runtime.h>
#include <hip/hip_bf16.h>

// Problem constants (from reference)
#define NE 8            // experts
#define NH 1024         // hidden
#define NF 2048         // ffn
#define NT_TOK 4096     // tokens = B*S
#define CAP 640         // ceil(1.25 * 4096 / 8) -- capacity semantics
#define CAPP 768        // padded rows per expert (multiple of 256)

typedef __bf16 bf16x8 __attribute__((ext_vector_type(8)));
typedef float f32x4 __attribute__((ext_vector_type(4)));

__device__ __forceinline__ ushort f2bf(float f) {
    union { float f; unsigned u; } v; v.f = f;
    unsigned r = (v.u + 0x7FFFu + ((v.u >> 16) & 1u)) >> 16;
    return (ushort)r;
}

// async global->LDS, 16B per lane, dest = wave-uniform base + lane*16
__device__ __forceinline__ void glds16(const ushort* g, ushort* l) {
    __builtin_amdgcn_global_load_lds((const __attribute__((address_space(1))) void*)g,
                                     (__attribute__((address_space(3))) void*)l,
                                     16, 0, 0);
}

#define MFMA_BF16 __builtin_amdgcn_mfma_f32_16x16x32_bf16

// ---------------------------------------------------------------------------
// K0: convert+transpose  in fp32 [R][C] -> out bf16 [C][R]
// Tile 128r x 64c, 256 thr. LDS [r][16 atoms of 4c], atom slot = ca ^ ((r>>3)&15)
// -> phase-1 8B writes and phase-2 column reads both bank-optimal.
// z: 0..7 -> tensor A (expert z), 8..15 -> tensor B (expert z-8).
// ---------------------------------------------------------------------------
__global__ __launch_bounds__(256) void k_conv_t(
    const float* __restrict__ inA, const float* __restrict__ inB,
    ushort* __restrict__ outA, ushort* __restrict__ outB, int R, int C)
{
    int z = blockIdx.z;
    const float* in = (z & 8) ? inB : inA;
    ushort* out = (z & 8) ? outB : outA;
    int e = z & 7;
    in  += (size_t)e * R * C;
    out += (size_t)e * R * C;
    int c0 = blockIdx.x * 64, r0 = blockIdx.y * 128;

    __shared__ __align__(16) ushort lds[128 * 64];   // 16 KB
    int t = threadIdx.x;
    int rr = t >> 4;             // 0..15
    int ci = t & 15;             // col-atom (4 cols)
    #pragma unroll
    for (int it = 0; it < 8; ++it) {
        int r = it * 16 + rr;
        float4 v = *(const float4*)(in + (size_t)(r0 + r) * C + c0 + ci * 4);
        union { ushort sh[4]; uint2 u; } p;
        p.sh[0] = f2bf(v.x); p.sh[1] = f2bf(v.y);
        p.sh[2] = f2bf(v.z); p.sh[3] = f2bf(v.w);
        int slot = ci ^ ((r >> 3) & 15);
        *(uint2*)&lds[r * 64 + slot * 4] = p.u;
    }
    __syncthreads();
    int g  = t >> 4;             // 0..15
    int ra = t & 15;             // r-atom (8 rows)
    #pragma unroll
    for (int it = 0; it < 4; ++it) {
        int c = it * 16 + g;
        int ca = c >> 2, cw = c & 3;
        union { ushort sh[8]; uint4 u; } p;
        #pragma unroll
        for (int j = 0; j < 8; ++j) {
            int r = ra * 8 + j;
            p.sh[j] = lds[r * 64 + ((ca ^ ((r >> 3) & 15)) << 2) + cw];
        }
        *(uint4*)(out + (size_t)(c0 + c) * R + r0 + ra * 8) = p.u;
    }
}

// ---------------------------------------------------------------------------
// K1: per-token LayerNorm (fp32) + router logits + softmax + top-2
// ---------------------------------------------------------------------------
__global__ __launch_bounds__(256) void k_ln_router(
    const float* __restrict__ x, const float* __restrict__ rw,
    const float* __restrict__ gamma, const float* __restrict__ beta,
    ushort* __restrict__ tok_bf, int* __restrict__ idx, float* __restrict__ wts)
{
    int t = blockIdx.x, tid = threadIdx.x;
    int lane = tid & 63, wid = tid >> 6;
    const float* xp = x + (size_t)t * NH;

    float4 v = *(const float4*)(xp + tid * 4);
    float xs[4] = {v.x, v.y, v.z, v.w};
    float s = xs[0] + xs[1] + xs[2] + xs[3];
    float q = xs[0]*xs[0] + xs[1]*xs[1] + xs[2]*xs[2] + xs[3]*xs[3];

    __shared__ float rs[4], rq[4], rl[4][8];
    #pragma unroll
    for (int o = 32; o; o >>= 1) { s += __shfl_xor(s, o); q += __shfl_xor(q, o); }
    if (lane == 0) { rs[wid] = s; rq[wid] = q; }
    __syncthreads();
    float S = rs[0] + rs[1] + rs[2] + rs[3];
    float Q = rq[0] + rq[1] + rq[2] + rq[3];
    float mean = S * (1.0f / NH);
    float var  = Q * (1.0f / NH) - mean * mean;
    float rstd = 1.0f / sqrtf(var + 1e-5f);

    float le[8] = {0,0,0,0,0,0,0,0};
    ushort tb[4];
    #pragma unroll
    for (int j = 0; j < 4; ++j) {
        int h = tid * 4 + j;
        float nh = (xs[j] - mean) * rstd * gamma[h] + beta[h];
        tb[j] = f2bf(nh);
        float4 r0 = *(const float4*)(rw + h * 8);
        float4 r1 = *(const float4*)(rw + h * 8 + 4);
        le[0] += nh * r0.x; le[1] += nh * r0.y; le[2] += nh * r0.z; le[3] += nh * r0.w;
        le[4] += nh * r1.x; le[5] += nh * r1.y; le[6] += nh * r1.z; le[7] += nh * r1.w;
    }
    union { ushort s2[4]; uint2 u2; } pk;
    pk.s2[0]=tb[0]; pk.s2[1]=tb[1]; pk.s2[2]=tb[2]; pk.s2[3]=tb[3];
    *(uint2*)(tok_bf + (size_t)t * NH + tid * 4) = pk.u2;

    #pragma unroll
    for (int o = 32; o; o >>= 1)
        #pragma unroll
        for (int e = 0; e < 8; ++e) le[e] += __shfl_xor(le[e], o);
    if (lane == 0)
        #pragma unroll
        for (int e = 0; e < 8; ++e) rl[wid][e] = le[e];
    __syncthreads();

    if (tid == 0) {
        float l[8];
        #pragma unroll
        for (int e = 0; e < 8; ++e) l[e] = rl[0][e] + rl[1][e] + rl[2][e] + rl[3][e];
        float mx = l[0];
        #pragma unroll
        for (int e = 1; e < 8; ++e) mx = fmaxf(mx, l[e]);
        float p[8], den = 0.f;
        #pragma unroll
        for (int e = 0; e < 8; ++e) { p[e] = expf(l[e] - mx); den += p[e]; }
        float rden = 1.0f / den;
        #pragma unroll
        for (int e = 0; e < 8; ++e) p[e] *= rden;
        int i0 = 0; float b0 = p[0];
        #pragma unroll
        for (int e = 1; e < 8; ++e) if (p[e] > b0) { b0 = p[e]; i0 = e; }
        int i1 = (i0 == 0) ? 1 : 0; float b1 = p[i1];
        #pragma unroll
        for (int e = 0; e < 8; ++e) if (e != i0 && p[e] > b1) { b1 = p[e]; i1 = e; }
        float sw = 1.0f / (b0 + b1);
        idx[2*t] = i0; idx[2*t+1] = i1;
        wts[2*t] = b0 * sw; wts[2*t+1] = b1 * sw;
    }
}

// ---------------------------------------------------------------------------
// K2: per-expert ordered compaction (stable by token index, capacity CAP)
// ---------------------------------------------------------------------------
__global__ __launch_bounds__(1024) void k_build_sel(
    const int* __restrict__ idx, int* __restrict__ sel)
{
    int e = blockIdx.x, tid = threadIdx.x;
    int lane = tid & 63, wid = tid >> 6;
    __shared__ int wsum[16], wpre[16], sbase;
    if (tid < CAPP) sel[e * CAPP + tid] = -1;
    if (tid == 0) sbase = 0;
    __syncthreads();

    for (int ch = 0; ch < NT_TOK / 1024; ++ch) {
        int t = ch * 1024 + tid;
        int m = (idx[2*t] == e || idx[2*t+1] == e) ? 1 : 0;
        int v = m;
        #pragma unroll
        for (int d = 1; d < 64; d <<= 1) {
            int u = __shfl_up(v, d);
            if (lane >= d) v += u;
        }
        if (lane == 63) wsum[wid] = v;
        __syncthreads();
        if (tid < 16) {
            int ws = wsum[tid], wv = ws;
            #pragma unroll
            for (int d = 1; d < 16; d <<= 1) {
                int u = __shfl_up(wv, d);
                if (tid >= d) wv += u;
            }
            wpre[tid] = wv - ws;
        }
        __syncthreads();
        int base0 = sbase;
        int slot = base0 + wpre[wid] + v - m;
        if (m && slot < CAP) sel[e * CAPP + slot] = t;
        __syncthreads();
        if (tid == 0) sbase = base0 + wpre[15] + wsum[15];
        __syncthreads();
    }
}

// ---------------------------------------------------------------------------
// K3: gather tokens into per-expert slot rows (zeros for invalid/pad slots)
// ---------------------------------------------------------------------------
__global__ __launch_bounds__(256) void k_gather(
    const int* __restrict__ sel, const ushort* __restrict__ tok,
    ushort* __restrict__ xin)
{
    int sIdx = blockIdx.x;
    int tokid = sel[sIdx];
    uint2 v = make_uint2(0u, 0u);
    if (tokid >= 0)
        v = *(const uint2*)(tok + (size_t)tokid * NH + threadIdx.x * 4);
    *(uint2*)(xin + (size_t)sIdx * NH + threadIdx.x * 4) = v;
}

// ===========================================================================
// GEMM1 (phase-split pipeline): hb = silu(xin@wg^T)*(xin@wu^T), fused.
// BM=256, BN=128 (gate AND up for the same f-columns, interleaved 32-wise in
// the 256-row B-tile: rows 64q+{0..31}=gate f0+32q.., 64q+{32..63}=up).
// 8 waves (2m x 4n), wave-out 128m x 64n (2 gate n-frags + 2 up n-frags).
// BK=32, 4 LDS buffers (128KB), stage tile t+2, ONE counted vmcnt(4) per
// K-tile at phase 3 (never 0 in steady state); phases 0-2 end in pure
// s_barrier. 4 phases/K-tile, 8 MFMA each, serpentine frag reuse.
// LDS atom swizzle: row a (64B = 4 atoms), chunk t at slot t ^ ((a>>1)&3);
// staged via inverse-swizzled global source + linear glds16 dest.
// ===========================================================================
__global__ __launch_bounds__(512, 2) void k_gemm1(
    const ushort* __restrict__ xin, const ushort* __restrict__ wgT,
    const ushort* __restrict__ wuT, ushort* __restrict__ hb)
{
    __shared__ __align__(16) ushort As[4][8192];   // 4 x 16KB: 256 rows x 32k
    __shared__ __align__(16) ushort Bs[4][8192];   // 4 x 16KB

    // XCD-chunked swizzle: 384 blocks -> 48 per XCD = exactly one expert
    int bid = blockIdx.x;
    int sw = (bid & 7) * 48 + (bid >> 3);
    int e  = sw / 48;
    int r48 = sw % 48;
    int mb = r48 >> 4, nb = r48 & 15;

    const ushort* A  = xin + (size_t)e * CAPP * NH + (size_t)mb * 256 * NH;
    int f0 = nb * 128;
    const ushort* Wg = wgT + (size_t)e * NF * NH;
    const ushort* Wu = wuT + (size_t)e * NF * NH;

    int tid = threadIdx.x, lane = tid & 63;
    int wid = tid >> 6;
    int wm = wid >> 2, wn = wid & 3;      // wm 0..1, wn 0..3
    int lr = lane & 15, lq = lane >> 4;

    // ---- staging source decomposition (inverse swizzle), fixed per thread
    int ar = tid >> 2;                                 // 0..127
    int tch = (tid & 3) ^ ((tid >> 3) & 3);
    int scol = tch * 8;                                // k-chunk elem offset
    const ushort* srcA0 = A + (size_t)ar * NH + scol;          // rows 0..127
    const ushort* srcA1 = A + (size_t)(128 + ar) * NH + scol;  // rows 128..255
    int b0 = ar, b1 = 128 + ar;
    const ushort* srcB0 = (((b0 >> 5) & 1) ? Wu : Wg)
        + (size_t)(f0 + ((b0 >> 6) << 5) + (b0 & 31)) * NH + scol;
    const ushort* srcB1 = (((b1 >> 5) & 1) ? Wu : Wg)
        + (size_t)(f0 + ((b1 >> 6) << 5) + (b1 & 31)) * NH + scol;
    int dl = tid * 8;    // ushort LDS offset, issue 0 (issue 1: +4096)

    // ---- frag read offsets (swizzled), loop-invariant
    int aoff[8], boff[4];
    #pragma unroll
    for (int m = 0; m < 8; ++m) {
        int a = wm * 128 + m * 16 + lr;
        aoff[m] = (a * 4 + (lq ^ ((a >> 1) & 3))) * 8;
    }
    #pragma unroll
    for (int n = 0; n < 4; ++n) {
        int b = wn * 64 + n * 16 + lr;
        boff[n] = (b * 4 + (lq ^ ((b >> 1) & 3))) * 8;
    }

    f32x4 acc[8][4] = {};
    const int NT = NH / 32;   // 32 K-tiles

    // prologue: stage tiles 0 and 1
    glds16(srcA0,      &As[0][dl]);
    glds16(srcA1,      &As[0][4096 + dl]);
    glds16(srcB0,      &Bs[0][dl]);
    glds16(srcB1,      &Bs[0][4096 + dl]);
    glds16(srcA0 + 32, &As[1][dl]);
    glds16(srcA1 + 32, &As[1][4096 + dl]);
    glds16(srcB0 + 32, &Bs[1][dl]);
    glds16(srcB1 + 32, &Bs[1][4096 + dl]);
    asm volatile("s_waitcnt vmcnt(4)" ::: "memory");
    __builtin_amdgcn_s_barrier();

    for (int t = 0; t < NT; ++t) {
        int buf = t & 3, sb = (t + 2) & 3;
        bool pf = (t + 2 < NT);
        size_t ko = (size_t)(t + 2) * 32;
        const ushort* Ab = &As[buf][0];
        const ushort* Bb = &Bs[buf][0];
        bf16x8 af0[4], af1[4], bf0[2], bf1[2];

        // phase 0: (m0..3, n0..1)  reads af0(4)+bf0(2)
        if (pf) glds16(srcA0 + ko, &As[sb][dl]);
        #pragma unroll
        for (int m = 0; m < 4; ++m) af0[m] = *(const bf16x8*)&Ab[aoff[m]];
        #pragma unroll
        for (int n = 0; n < 2; ++n) bf0[n] = *(const bf16x8*)&Bb[boff[n]];
        __builtin_amdgcn_s_setprio(1);
        #pragma unroll
        for (int m = 0; m < 4; ++m)
            #pragma unroll
            for (int n = 0; n < 2; ++n)
                acc[m][n] = MFMA_BF16(af0[m], bf0[n], acc[m][n], 0, 0, 0);
        __builtin_amdgcn_s_setprio(0);
        __builtin_amdgcn_s_barrier();

        // phase 1: (m4..7, n0..1)  reads af1(4)
        if (pf) glds16(srcA1 + ko, &As[sb][4096 + dl]);
        #pragma unroll
        for (int m = 0; m < 4; ++m) af1[m] = *(const bf16x8*)&Ab[aoff[4 + m]];
        __builtin_amdgcn_s_setprio(1);
        #pragma unroll
        for (int m = 0; m < 4; ++m)
            #pragma unroll
            for (int n = 0; n < 2; ++n)
                acc[4 + m][n] = MFMA_BF16(af1[m], bf0[n], acc[4 + m][n], 0, 0, 0);
        __builtin_amdgcn_s_setprio(0);
        __builtin_amdgcn_s_barrier();

        // phase 2: (m4..7, n2..3)  reads bf1(2)
        if (pf) glds16(srcB0 + ko, &Bs[sb][dl]);
        #pragma unroll
        for (int n = 0; n < 2; ++n) bf1[n] = *(const bf16x8*)&Bb[boff[2 + n]];
        __builtin_amdgcn_s_setprio(1);
        #pragma unroll
        for (int m = 0; m < 4; ++m)
            #pragma unroll
            for (int n = 0; n < 2; ++n)
                acc[4 + m][2 + n] = MFMA_BF16(af1[m], bf1[n], acc[4 + m][2 + n], 0, 0, 0);
        __builtin_amdgcn_s_setprio(0);
        __builtin_amdgcn_s_barrier();

        // phase 3: (m0..3, n2..3)  no reads; counted vmcnt gate for tile t+1
        if (pf) glds16(srcB1 + ko, &Bs[sb][4096 + dl]);
        __builtin_amdgcn_s_setprio(1);
        #pragma unroll
        for (int m = 0; m < 4; ++m)
            #pragma unroll
            for (int n = 0; n < 2; ++n)
                acc[m][2 + n] = MFMA_BF16(af0[m], bf1[n], acc[m][2 + n], 0, 0, 0);
        __builtin_amdgcn_s_setprio(0);
        if (pf) asm volatile("s_waitcnt vmcnt(4)" ::: "memory");
        else    asm volatile("s_waitcnt vmcnt(0)" ::: "memory");
        __builtin_amdgcn_s_barrier();
    }

    // epilogue: silu(gate)*up, wave-local pairing (acc[.][n] gate, [.][n+2] up)
    ushort* outp = hb + (size_t)e * CAPP * NF + (size_t)(mb * 256) * NF + f0;
    #pragma unroll
    for (int m = 0; m < 8; ++m)
        #pragma unroll
        for (int n = 0; n < 2; ++n)
            #pragma unroll
            for (int r = 0; r < 4; ++r) {
                int row = wm * 128 + m * 16 + lq * 4 + r;
                int col = wn * 32 + n * 16 + lr;
                float g = acc[m][n][r], u = acc[m][n + 2][r];
                float sg = g / (1.0f + expf(-g));
                outp[(size_t)row * NF + col] = f2bf(sg * u);
            }
}

// ---------------------------------------------------------------------------
// GEMM2: eo[e] = hb[e] @ wdT[e]^T   M=CAP(640 of CAPP rows), N=NH, K=NF
// BM=128, BN=128, 256 thr (4 waves 2x2). Verified R4 structure + XCD swizzle.
// ---------------------------------------------------------------------------
__global__ __launch_bounds__(256, 4) void k_gemm2(
    const ushort* __restrict__ hb, const ushort* __restrict__ wdT,
    float* __restrict__ eo)
{
    __shared__ __align__(16) ushort As[3][4096];
    __shared__ __align__(16) ushort Bs[3][4096];

    // 320 blocks -> 40 per XCD = one expert's gemm2
    int bid = blockIdx.x;
    int sw = (bid & 7) * 40 + (bid >> 3);
    int e = sw / 40;
    int r40 = sw % 40;
    int mb = r40 >> 3, nb = r40 & 7;

    const ushort* A = hb  + (size_t)e * CAPP * NF + (size_t)mb * 128 * NF;
    const ushort* B = wdT + (size_t)e * NH * NF + (size_t)nb * 128 * NF;

    int tid = threadIdx.x, lane = tid & 63, wid = tid >> 6;
    int wm = wid >> 1, wn = wid & 1;
    int lr = lane & 15, lq = lane >> 4;

    int Rg = tid >> 3;                    // 0..31
    int ug = (tid & 7) ^ (Rg & 7);
    int sROW2 = ug >> 2, sCOL = (ug & 3) * 8;
    size_t goff0 = (size_t)(2 * Rg + sROW2) * NF + sCOL;
    size_t goff1 = (size_t)(2 * (32 + Rg) + sROW2) * NF + sCOL;
    int ldsu = tid * 8;

    int aoff[4], boff[4];
    #pragma unroll
    for (int m = 0; m < 4; ++m) {
        int a = wm * 64 + m * 16 + lr;
        int Rr = a >> 1;
        int sl = (((a & 1) << 2) | lq) ^ (Rr & 7);
        aoff[m] = Rr * 64 + sl * 8;
    }
    #pragma unroll
    for (int n = 0; n < 4; ++n) {
        int c = wn * 64 + n * 16 + lr;
        int Rr = c >> 1;
        int sl = (((c & 1) << 2) | lq) ^ (Rr & 7);
        boff[n] = Rr * 64 + sl * 8;
    }

    f32x4 acc[4][4] = {};
    const int NT = NF / 32;   // 64 K-tiles

    #define STG2(t, s) do { size_t _k = (size_t)(t) * 32;                       \
        glds16(A + goff0 + _k, &As[s][ldsu]);                                   \
        glds16(A + goff1 + _k, &As[s][2048 + ldsu]);                            \
        glds16(B + goff0 + _k, &Bs[s][ldsu]);                                   \
        glds16(B + goff1 + _k, &Bs[s][2048 + ldsu]); } while (0)

    STG2(0, 0); STG2(1, 1);
    asm volatile("s_waitcnt vmcnt(4)" ::: "memory");
    asm volatile("s_barrier" ::: "memory");

    int sl_c = 0, sl_p = 2;
    for (int t = 0; t < NT; ++t) {
        bool pf = (t + 2 < NT);
        if (pf) STG2(t + 2, sl_p);
        const ushort* Ab = &As[sl_c][0];
        const ushort* Bb = &Bs[sl_c][0];
        bf16x8 af[4], bf_[4];
        #pragma unroll
        for (int m = 0; m < 4; ++m) af[m] = *(const bf16x8*)&Ab[aoff[m]];
        #pragma unroll
        for (int n = 0; n < 4; ++n) bf_[n] = *(const bf16x8*)&Bb[boff[n]];
        __builtin_amdgcn_s_setprio(1);
        #pragma unroll
        for (int m = 0; m < 4; ++m)
            #pragma unroll
            for (int n = 0; n < 4; ++n)
                acc[m][n] = MFMA_BF16(af[m], bf_[n], acc[m][n], 0, 0, 0);
        __builtin_amdgcn_s_setprio(0);
        if (pf) asm volatile("s_waitcnt vmcnt(4)" ::: "memory");
        else    asm volatile("s_waitcnt vmcnt(0)" ::: "memory");
        asm volatile("s_barrier" ::: "memory");
        sl_c = (sl_c == 2) ? 0 : sl_c + 1;
        sl_p = (sl_p == 2) ? 0 : sl_p + 1;
    }
    #undef STG2

    float* outp = eo + (size_t)e * CAP * NH + (size_t)mb * 128 * NH + nb * 128;
    #pragma unroll
    for (int m = 0; m < 4; ++m)
        #pragma unroll
        for (int n = 0; n < 4; ++n)
            #pragma unroll
            for (int r = 0; r < 4; ++r) {
                int row = wm * 64 + m * 16 + lq * 4 + r;
                int col = wn * 64 + n * 16 + lr;
                outp[(size_t)row * NH + col] = acc[m][n][r];
            }
}

// ---------------------------------------------------------------------------
// K5: out[t] = x[t] + w0*eo[e0][min(t,CAP-1)] + w1*eo[e1][min(t,CAP-1)]
// (reference gathers by CLAMPED TOKEN INDEX, not dispatch slot)
// ---------------------------------------------------------------------------
__global__ __launch_bounds__(256) void k_final(
    const float* __restrict__ x, const float* __restrict__ eo,
    const int* __restrict__ idx, const float* __restrict__ wts,
    float* __restrict__ out)
{
    int t = blockIdx.x;
    int c = (t < CAP - 1) ? t : (CAP - 1);
    int e0 = idx[2*t], e1 = idx[2*t+1];
    float w0 = wts[2*t], w1 = wts[2*t+1];
    int h = threadIdx.x * 4;
    float4 xv = *(const float4*)(x + (size_t)t * NH + h);
    float4 a = *(const float4*)(eo + ((size_t)e0 * CAP + c) * NH + h);
    float4 b = *(const float4*)(eo + ((size_t)e1 * CAP + c) * NH + h);
    float4 o;
    o.x = xv.x + w0 * a.x + w1 * b.x;
    o.y = xv.y + w0 * a.y + w1 * b.y;
    o.z = xv.z + w0 * a.z + w1 * b.z;
    o.w = xv.w + w0 * a.w + w1 * b.w;
    *(float4*)(out + (size_t)t * NH + h) = o;
}

// ---------------------------------------------------------------------------
extern "C" void kernel_launch(void* const* d_in, const int* in_sizes, int n_in,
                              void* d_out, int out_size, void* d_ws, size_t ws_size,
                              hipStream_t stream)
{
    const float* x     = (const float*)d_in[0];
    const float* rw    = (const float*)d_in[1];
    const float* wg    = (const float*)d_in[2];
    const float* wu    = (const float*)d_in[3];
    const float* wd    = (const float*)d_in[4];
    const float* gamma = (const float*)d_in[5];
    const float* beta  = (const float*)d_in[6];
    float* out = (float*)d_out;

    char* ws = (char*)d_ws;
    // eo (written by gemm2) aliases tok_bf (dead after k_gather)
    float*  eo     = (float*) (ws);                 // 8*640*1024*4 = 20,971,520
    ushort* tok_bf = (ushort*)(ws);                 //  8,388,608 (alias)
    ushort* xin    = (ushort*)(ws +  20971520);     // 8*768*1024*2 = 12,582,912
    ushort* hb     = (ushort*)(ws +  33554432);     // 8*768*2048*2 = 25,165,824
    ushort* wgT    = (ushort*)(ws +  58720256);     // 33,554,432
    ushort* wuT    = (ushort*)(ws +  92274688);     // 33,554,432
    ushort* wdT    = (ushort*)(ws + 125829120);     // 33,554,432
    int*    idx    = (int*)   (ws + 159383552);     //     32,768
    float*  wts    = (float*) (ws + 159416320);     //     32,768
    int*    sel    = (int*)   (ws + 159449088);     // 8*768*4 = 24,576
    // total ~159.5 MB

    // weight convert+transpose (exact grids, no wasted blocks)
    k_conv_t<<<dim3(NF / 64, NH / 128, 16), 256, 0, stream>>>(wg, wu, wgT, wuT, NH, NF);
    k_conv_t<<<dim3(NH / 64, NF / 128, 8),  256, 0, stream>>>(wd, wd, wdT, wdT, NF, NH);

    k_ln_router<<<NT_TOK, 256, 0, stream>>>(x, rw, gamma, beta, tok_bf, idx, wts);
    k_build_sel<<<NE, 1024, 0, stream>>>(idx, sel);
    k_gather<<<NE * CAPP, 256, 0, stream>>>(sel, tok_bf, xin);
    k_gemm1<<<384, 512, 0, stream>>>(xin, wgT, wuT, hb);
    k_gemm2<<<320, 256, 0, stream>>>(hb, wdT, eo);
    k_final<<<NT_TOK, 256, 0, stream>>>(x, eo, idx, wts, out);
}